// Round 9
// baseline (1680.157 us; speedup 1.0000x reference)
//
#include <hip/hip_runtime.h>

#define NODES   131072
#define EDGES   2097152
#define H       128
#define NB      32        // graphs
#define PP      4096      // nodes per problem graph

typedef short bf16x8 __attribute__((ext_vector_type(8)));
typedef float f32x4  __attribute__((ext_vector_type(4)));
typedef unsigned short u16;

// packed-weight element offsets
#define RZE 65536
#define AIE 16384
#define AHE 16384
#define LYRE (RZE + AIE + AHE)   // 98304 per conv layer

// ============================================================================
// CSR build, histogram-free (round-7 analysis: global-atomic hist cost 82us /
// 65MB sector RMW). Partition p = dst>>10, fixed slab CAPP; bin1 stages with
// contiguous-run writes; bin2 builds rowptr slice via LDS hist+scan and
// scatters (one block owns each 64KB epack slice -> no cross-XCD write amp).
// ============================================================================
#define CAPP 18432

__global__ __launch_bounds__(128) void gnn_pinit(int* __restrict__ pcur) {
  pcur[threadIdx.x] = threadIdx.x * CAPP;
}

// Staged record: .x = src(17b)<<15 | round(ew*32768), .y = dst
#define B1_BLOCKS 256
#define B1_TILES  4
__global__ __launch_bounds__(256) void gnn_bin1(const int* __restrict__ src, const int* __restrict__ dst,
                                                const float* __restrict__ ew, int* __restrict__ pcur,
                                                uint2* __restrict__ stage) {
  __shared__ int hist[128];
  __shared__ int pbase[128];
  const int tid = threadIdx.x;
  for (int t = 0; t < B1_TILES; ++t) {
    if (tid < 128) hist[tid] = 0;
    __syncthreads();
    const int ebase = blockIdx.x * (B1_TILES * 2048) + t * 2048;
    int parts[8], ranks[8];
    uint2 recs[8];
#pragma unroll
    for (int i = 0; i < 8; ++i) {
      int e = ebase + i * 256 + tid;
      int d = dst[e];
      int s = src[e];
      float w = ew[e];
      int wq = (int)fminf(w * 32768.f + 0.5f, 32767.f);
      parts[i] = d >> 10;
      recs[i].x = ((unsigned)s << 15) | (unsigned)wq;
      recs[i].y = (unsigned)d;
      ranks[i] = atomicAdd(&hist[parts[i]], 1);
    }
    __syncthreads();
    if (tid < 128) {
      int c = hist[tid];
      pbase[tid] = c ? atomicAdd(&pcur[tid], c) : 0;
    }
    __syncthreads();
#pragma unroll
    for (int i = 0; i < 8; ++i)
      stage[pbase[parts[i]] + ranks[i]] = recs[i];
    __syncthreads();
  }
}

__global__ __launch_bounds__(128) void gnn_pscan(const int* __restrict__ pcur, int* __restrict__ pbase) {
  __shared__ int s[128];
  int t = threadIdx.x;
  int v = pcur[t] - t * CAPP;
  s[t] = v; __syncthreads();
  for (int o = 1; o < 128; o <<= 1) {
    int u = (t >= o) ? s[t - o] : 0;
    __syncthreads();
    s[t] += u;
    __syncthreads();
  }
  pbase[t] = s[t] - v;
}

__global__ __launch_bounds__(256) void gnn_bin2(const uint2* __restrict__ stage,
                                                const int* __restrict__ pcur,
                                                const int* __restrict__ pbase,
                                                int* __restrict__ rowptr,
                                                unsigned* __restrict__ epack) {
  __shared__ int h[1024];
  __shared__ int ws[256];
  const int tid = threadIdx.x;
  const int p = blockIdx.x;
  const int node0 = p << 10;
  const int s0 = p * CAPP;
  const int cnt = pcur[p] - s0;
  const int gbase = pbase[p];
#pragma unroll
  for (int i = 0; i < 4; ++i) h[i * 256 + tid] = 0;
  __syncthreads();
  for (int r = tid; r < cnt; r += 256)
    atomicAdd(&h[(int)stage[s0 + r].y - node0], 1);
  __syncthreads();
  int a0 = h[tid * 4 + 0], a1 = h[tid * 4 + 1], a2 = h[tid * 4 + 2], a3 = h[tid * 4 + 3];
  int s1 = a0 + a1, s2 = s1 + a2, s3 = s2 + a3;
  ws[tid] = s3;
  __syncthreads();
  for (int o = 1; o < 256; o <<= 1) {
    int u = (tid >= o) ? ws[tid - o] : 0;
    __syncthreads();
    ws[tid] += u;
    __syncthreads();
  }
  int eb = gbase + (tid ? ws[tid - 1] : 0);
  int4 rp;
  rp.x = eb; rp.y = eb + a0; rp.z = eb + s1; rp.w = eb + s2;
  *(int4*)(rowptr + node0 + tid * 4) = rp;
  h[tid * 4 + 0] = rp.x; h[tid * 4 + 1] = rp.y; h[tid * 4 + 2] = rp.z; h[tid * 4 + 3] = rp.w;
  if (p == 127 && tid == 255) rowptr[NODES] = EDGES;
  __syncthreads();
  for (int r = tid; r < cnt; r += 256) {
    uint2 q = stage[s0 + r];
    int pos = atomicAdd(&h[(int)q.y - node0], 1);
    epack[pos] = q.x;
  }
}

// ============================================================================
// bf16 helpers
// ============================================================================
__device__ __forceinline__ unsigned gnn_pack2bf(float a, float b) {
  union { float f; unsigned u; } x, y; x.f = a; y.f = b;
  unsigned ua = (x.u + 0x7FFFu + ((x.u >> 16) & 1u)) >> 16;
  unsigned ub = (y.u + 0x7FFFu + ((y.u >> 16) & 1u)) >> 16;
  return ua | (ub << 16);
}

__device__ __forceinline__ u16 gnn_f2bf(float a) {
  union { float f; unsigned u; } x; x.f = a;
  return (u16)((x.u + 0x7FFFu + ((x.u >> 16) & 1u)) >> 16);
}

__device__ __forceinline__ float gnn_bf2f(u16 h) {
  union { unsigned u; float f; } x; x.u = ((unsigned)h) << 16; return x.f;
}

__device__ __forceinline__ float gnn_sig(float x)  { return 1.f / (1.f + __expf(-x)); }
__device__ __forceinline__ float gnn_tanh(float x) { return 1.f - 2.f / (1.f + __expf(2.f * x)); }

// ============================================================================
// per-node edge aggregation (lane covers cols {2*lane, 2*lane+1}).
// 16-deep software pipeline, cascade 16/8/4/serial.
// ============================================================================
__device__ __forceinline__ void gnn_agg_edge(const u16* __restrict__ X, unsigned q, int lane,
                                             float& a0, float& a1) {
  unsigned pv = *(const unsigned*)(X + (long)(q >> 15) * H + lane * 2);
  float w = (float)(q & 0x7FFFu) * (1.f / 32768.f);
  union { unsigned u; float f; } lo, hi;
  lo.u = pv << 16; hi.u = pv & 0xFFFF0000u;
  a0 = fmaf(w, lo.f, a0);
  a1 = fmaf(w, hi.f, a1);
}

__device__ __forceinline__ unsigned gnn_agg_run(const u16* __restrict__ X,
                                                const unsigned* __restrict__ epack,
                                                int e0, int e1, int lane) {
  float a0 = 0.f, a1 = 0.f;
  int e = e0;
  for (; e + 16 <= e1; e += 16) {
    unsigned q[16];
#pragma unroll
    for (int j = 0; j < 16; ++j) q[j] = epack[e + j];
    unsigned p[16];
#pragma unroll
    for (int j = 0; j < 16; ++j) p[j] = *(const unsigned*)(X + (long)(q[j] >> 15) * H + lane * 2);
#pragma unroll
    for (int j = 0; j < 16; ++j) {
      float w = (float)(q[j] & 0x7FFFu) * (1.f / 32768.f);
      union { unsigned u; float f; } lo, hi;
      lo.u = p[j] << 16; hi.u = p[j] & 0xFFFF0000u;
      a0 = fmaf(w, lo.f, a0);
      a1 = fmaf(w, hi.f, a1);
    }
  }
  if (e + 8 <= e1) {
    unsigned q[8];
#pragma unroll
    for (int j = 0; j < 8; ++j) q[j] = epack[e + j];
    unsigned p[8];
#pragma unroll
    for (int j = 0; j < 8; ++j) p[j] = *(const unsigned*)(X + (long)(q[j] >> 15) * H + lane * 2);
#pragma unroll
    for (int j = 0; j < 8; ++j) {
      float w = (float)(q[j] & 0x7FFFu) * (1.f / 32768.f);
      union { unsigned u; float f; } lo, hi;
      lo.u = p[j] << 16; hi.u = p[j] & 0xFFFF0000u;
      a0 = fmaf(w, lo.f, a0);
      a1 = fmaf(w, hi.f, a1);
    }
    e += 8;
  }
  if (e + 4 <= e1) {
    unsigned q[4];
#pragma unroll
    for (int j = 0; j < 4; ++j) q[j] = epack[e + j];
#pragma unroll
    for (int j = 0; j < 4; ++j) gnn_agg_edge(X, q[j], lane, a0, a1);
    e += 4;
  }
  for (; e < e1; ++e) gnn_agg_edge(X, epack[e], lane, a0, a1);
  return gnn_pack2bf(a0, a1);
}

// ============================================================================
// weight prep (consolidated): Wc[l] = W[l] @ wi.T ; whT = wh.T
// ============================================================================
__global__ __launch_bounds__(384) void gnn_prep_wc_all(const float* __restrict__ c1W, const float* __restrict__ c1wi,
                                                       const float* __restrict__ c2W, const float* __restrict__ c2wi,
                                                       float* __restrict__ Wc) {
  __shared__ float wrow[128];
  int l = blockIdx.x >> 7, k = blockIdx.x & 127, j = threadIdx.x;
  const float* Wl = (l < 2 ? c1W : c2W) + (l & 1) * 128 * 128;
  const float* wi = l < 2 ? c1wi : c2wi;
  if (j < 128) wrow[j] = Wl[k * 128 + j];
  __syncthreads();
  float acc = 0.f;
  for (int m = 0; m < 128; ++m) acc = fmaf(wrow[m], wi[j * 128 + m], acc);
  Wc[(long)l * 49152 + k * 384 + j] = acc;
}

__global__ __launch_bounds__(384) void gnn_prep_whT(const float* __restrict__ wh1, const float* __restrict__ wh2,
                                                    float* __restrict__ whT) {
  int c = blockIdx.x >> 7, k = blockIdx.x & 127, j = threadIdx.x;
  const float* wh = c ? wh2 : wh1;
  whT[((long)c * 128 + k) * 384 + j] = wh[j * 128 + k];
}

// ============================================================================
// MFMA fragment plumbing
// A-frag (16x16x32): A[m=lane&15][k=(lane>>4)*8+j]; B[k][n=lane&15]
// C/D: col=lane&15, row=(lane>>4)*4+reg
// LDS A staging: slot(ktq,row) = ktq*64 + (row ^ (ktq&7)), 16B/slot
// ============================================================================
template<int K>
__device__ __forceinline__ void gnn_stage_bf(const u16* __restrict__ A, long row0,
                                             u16* lds, int tid) {
  constexpr int CH = K / 8;
#pragma unroll
  for (int it = 0; it < (64 * CH) / 256; ++it) {
    int c = it * 256 + tid;
    int row = c / CH, ktq = c % CH;
    uint4 v = *(const uint4*)(A + (row0 + row) * K + ktq * 8);
    int slot = ktq * 64 + (row ^ (ktq & 7));
    *(uint4*)(lds + slot * 8) = v;
  }
}

__device__ __forceinline__ bf16x8 gnn_afrag(const u16* lds, int rt, int ktq, int l16) {
  int slot = ktq * 64 + ((rt * 16 + l16) ^ (ktq & 7));
  return *(const bf16x8*)(lds + slot * 8);
}

__device__ __forceinline__ bf16x8 gnn_bfrag(const u16* __restrict__ pk,
                                            int ct, int kt, int KT, int lane) {
  return *(const bf16x8*)(pk + (((long)(ct * KT + kt)) * 64 + lane) * 8);
}

// scalar store of a C-layout element into A-layout LDS (for GEMM chaining)
__device__ __forceinline__ void gnn_lds_put(u16* lds, int row, int col, float v) {
  int kq = col >> 3, of = col & 7;
  lds[(kq * 64 + (row ^ (kq & 7))) * 8 + of] = gnn_f2bf(v);
}

__device__ __forceinline__ float gnn_lds_get(const u16* lds, int row, int col) {
  int kq = col >> 3, of = col & 7;
  return gnn_bf2f(lds[(kq * 64 + (row ^ (kq & 7))) * 8 + of]);
}

// ============================================================================
// weight packing to MFMA B-frag bf16 (consolidated kernels)
// ============================================================================
__device__ __forceinline__ void gnn_pack_body(const float* __restrict__ W0, const float* __restrict__ W1,
                                              int ksplit, int LD, int coff, int KT, int b, int lane,
                                              u16* __restrict__ dst) {
  int kt = b % KT, ct = b / KT;
  int col = ct * 16 + (lane & 15) + coff;
  int kb = kt * 32 + ((lane >> 4) & 3) * 8;
  u16 h[8];
#pragma unroll
  for (int j = 0; j < 8; ++j) {
    int k = kb + j;
    float v = (k < ksplit) ? W0[(long)k * LD + col] : W1[(long)(k - ksplit) * LD + col];
    h[j] = gnn_f2bf(v);
  }
  uint4 o;
  o.x = (unsigned)h[0] | ((unsigned)h[1] << 16);
  o.y = (unsigned)h[2] | ((unsigned)h[3] << 16);
  o.z = (unsigned)h[4] | ((unsigned)h[5] << 16);
  o.w = (unsigned)h[6] | ((unsigned)h[7] << 16);
  ((uint4*)dst)[(long)b * 64 + lane] = o;
}

// 4 conv layers x (rz 128 + ai 32 + ah 32) = 768 blocks
__global__ __launch_bounds__(64) void gnn_pack_layers(const float* __restrict__ Wc, const float* __restrict__ whT,
                                                      u16* __restrict__ pk) {
  int l = blockIdx.x / 192, r = blockIdx.x % 192;
  int lane = threadIdx.x;
  const float* Wcl = Wc + (long)l * 49152;
  const float* whl = whT + (long)(l >> 1) * 49152;
  u16* base = pk + (long)l * LYRE;
  if (r < 128)      gnn_pack_body(Wcl, whl, 128, 384, 0,   8, r,       lane, base);
  else if (r < 160) gnn_pack_body(Wcl, Wcl, 128, 384, 256, 4, r - 128, lane, base + RZE);
  else              gnn_pack_body(whl, whl, 128, 384, 256, 4, r - 160, lane, base + RZE + AIE);
}

// pe2(32) pg1(32) pg2(32) pl1(64) pl2(64) = 224 blocks
__global__ __launch_bounds__(64) void gnn_pack_misc(const float* __restrict__ We2, const float* __restrict__ Wg1,
                                                    const float* __restrict__ Wg2, const float* __restrict__ Wl1,
                                                    const float* __restrict__ Wl2, u16* __restrict__ pk) {
  int b = blockIdx.x, lane = threadIdx.x;
  u16* pe2 = pk + 4 * LYRE;
  if (b < 32)       gnn_pack_body(We2, We2, 128, 128, 0, 4, b,       lane, pe2);
  else if (b < 64)  gnn_pack_body(Wg1, Wg1, 128, 128, 0, 4, b - 32,  lane, pe2 + 16384);
  else if (b < 96)  gnn_pack_body(Wg2, Wg2, 128, 128, 0, 4, b - 64,  lane, pe2 + 32768);
  else if (b < 160) gnn_pack_body(Wl1, Wl1, 128, 256, 0, 4, b - 96,  lane, pe2 + 49152);
  else              gnn_pack_body(Wl2, Wl2, 256, 128, 0, 8, b - 160, lane, pe2 + 81920);
}

// ============================================================================
// MFMA GEMM (emb2 only now): C = relu(A@Wpk + bias), 64-row blocks
// ============================================================================
template<int K, int N, int ACT>
__global__ __launch_bounds__(256) void gnn_mgemm(const u16* __restrict__ A,
                                                 const u16* __restrict__ pk,
                                                 const float* __restrict__ bias,
                                                 u16* __restrict__ C) {
  constexpr int KT = K / 32;
  constexpr int CT = N / 64;
  __shared__ u16 As[64 * K];
  const int tid = threadIdx.x;
  const int lane = tid & 63, wave = tid >> 6;
  const int quad = lane >> 4, l16 = lane & 15;
  const long row0 = (long)blockIdx.x * 64;
  gnn_stage_bf<K>(A, row0, As, tid);
  __syncthreads();

  f32x4 zero4 = {0.f, 0.f, 0.f, 0.f};
  f32x4 acc[4][CT];
#pragma unroll
  for (int rt = 0; rt < 4; ++rt)
#pragma unroll
    for (int ct = 0; ct < CT; ++ct) acc[rt][ct] = zero4;

#pragma unroll
  for (int kt = 0; kt < KT; ++kt) {
    int ktq = kt * 4 + quad;
    bf16x8 af[4];
#pragma unroll
    for (int rt = 0; rt < 4; ++rt) af[rt] = gnn_afrag(As, rt, ktq, l16);
#pragma unroll
    for (int ct = 0; ct < CT; ++ct) {
      bf16x8 bf = gnn_bfrag(pk, wave * CT + ct, kt, KT, lane);
#pragma unroll
      for (int rt = 0; rt < 4; ++rt)
        acc[rt][ct] = __builtin_amdgcn_mfma_f32_16x16x32_bf16(af[rt], bf, acc[rt][ct], 0, 0, 0);
    }
  }

#pragma unroll
  for (int ct = 0; ct < CT; ++ct) {
    int col = (wave * CT + ct) * 16 + l16;
    float bv = bias[col];
#pragma unroll
    for (int rt = 0; rt < 4; ++rt) {
      long row = row0 + rt * 16 + quad * 4;
#pragma unroll
      for (int r = 0; r < 4; ++r) {
        float v = acc[rt][ct][r] + bv;
        if (ACT) v = fmaxf(v, 0.f);
        C[(row + r) * N + col] = gnn_f2bf(v);
      }
    }
  }
}

// ============================================================================
// FUSED agg + GRU: block = 64 nodes. Phase 1: stage X->Xs; each wave
// aggregates 16 nodes' edges directly into swizzled Ts (kills the 32MB T
// round-trip per layer; agg VMEM overlaps other blocks' GRU MFMA).
// Phase 2: GRU gates via MFMA (pkRZ fused r|z over [T|X], pkAI, pkAH),
// h read from Xs LDS. Y = GRU output (optional relu).
// ============================================================================
template<int RELU>
__global__ __launch_bounds__(256) void gnn_aggru(const u16* __restrict__ X,
                                                 const int* __restrict__ rowptr,
                                                 const unsigned* __restrict__ epack,
                                                 const u16* __restrict__ pkRZ,
                                                 const u16* __restrict__ pkAI,
                                                 const u16* __restrict__ pkAH,
                                                 const float* __restrict__ bi, const float* __restrict__ bh,
                                                 u16* __restrict__ Y) {
  __shared__ u16 Ts[64 * 128];
  __shared__ u16 Xs[64 * 128];
  const int tid = threadIdx.x;
  const int lane = tid & 63, wave = tid >> 6;
  const int quad = lane >> 4, l16 = lane & 15;
  const long row0 = (long)blockIdx.x * 64;
  gnn_stage_bf<128>(X, row0, Xs, tid);

  // ---- agg phase: wave w owns rows [w*16, w*16+16) ----
  {
    const int kq = lane >> 2;            // this lane's col chunk (cols 2*lane,2*lane+1)
    const int of = (lane & 3) * 2;       // u16 offset in chunk
    for (int i = 0; i < 16; ++i) {
      int row = wave * 16 + i;
      long node = row0 + row;
      int e0 = rowptr[node], e1 = rowptr[node + 1];
      unsigned pv = gnn_agg_run(X, epack, e0, e1, lane);
      *(unsigned*)(Ts + (kq * 64 + (row ^ (kq & 7))) * 8 + of) = pv;
    }
  }
  __syncthreads();

  // ---- GRU phase ----
  f32x4 zero4 = {0.f, 0.f, 0.f, 0.f};
  f32x4 ai[4][2], ah[4][2], rr[4][2];
#pragma unroll
  for (int rt = 0; rt < 4; ++rt)
#pragma unroll
    for (int c = 0; c < 2; ++c) { ai[rt][c] = zero4; ah[rt][c] = zero4; rr[rt][c] = zero4; }

#pragma unroll
  for (int kt = 0; kt < 4; ++kt) {
    int ktq = kt * 4 + quad;
    bf16x8 tf[4], xf[4];
#pragma unroll
    for (int rt = 0; rt < 4; ++rt) { tf[rt] = gnn_afrag(Ts, rt, ktq, l16); xf[rt] = gnn_afrag(Xs, rt, ktq, l16); }
#pragma unroll
    for (int c = 0; c < 2; ++c) {
      int ct = wave * 2 + c;
      bf16x8 bAI = gnn_bfrag(pkAI, ct, kt, 4, lane);
      bf16x8 bAH = gnn_bfrag(pkAH, ct, kt, 4, lane);
      bf16x8 bRT = gnn_bfrag(pkRZ, ct, kt,     8, lane);
      bf16x8 bRX = gnn_bfrag(pkRZ, ct, kt + 4, 8, lane);
#pragma unroll
      for (int rt = 0; rt < 4; ++rt) {
        ai[rt][c] = __builtin_amdgcn_mfma_f32_16x16x32_bf16(tf[rt], bAI, ai[rt][c], 0, 0, 0);
        ah[rt][c] = __builtin_amdgcn_mfma_f32_16x16x32_bf16(xf[rt], bAH, ah[rt][c], 0, 0, 0);
        rr[rt][c] = __builtin_amdgcn_mfma_f32_16x16x32_bf16(tf[rt], bRT, rr[rt][c], 0, 0, 0);
        rr[rt][c] = __builtin_amdgcn_mfma_f32_16x16x32_bf16(xf[rt], bRX, rr[rt][c], 0, 0, 0);
      }
    }
  }

  float brz[2], bzz[2], bin_[2], bhn[2];
#pragma unroll
  for (int c = 0; c < 2; ++c) {
    int col = (wave * 2 + c) * 16 + l16;
    brz[c]  = bi[col] + bh[col];
    bzz[c]  = bi[128 + col] + bh[128 + col];
    bin_[c] = bi[256 + col];
    bhn[c]  = bh[256 + col];
  }

  // n = tanh(ai + bi_n + r*(ah + bh_n))   (n overwrites ai)
#pragma unroll
  for (int rt = 0; rt < 4; ++rt)
#pragma unroll
    for (int c = 0; c < 2; ++c)
#pragma unroll
      for (int r = 0; r < 4; ++r) {
        float rv = gnn_sig(rr[rt][c][r] + brz[c]);
        ai[rt][c][r] = gnn_tanh(ai[rt][c][r] + bin_[c] + rv * (ah[rt][c][r] + bhn[c]));
      }

  // z gate
  f32x4 zz[4][2];
#pragma unroll
  for (int rt = 0; rt < 4; ++rt)
#pragma unroll
    for (int c = 0; c < 2; ++c) zz[rt][c] = zero4;
#pragma unroll
  for (int kt = 0; kt < 4; ++kt) {
    int ktq = kt * 4 + quad;
    bf16x8 tf[4], xf[4];
#pragma unroll
    for (int rt = 0; rt < 4; ++rt) { tf[rt] = gnn_afrag(Ts, rt, ktq, l16); xf[rt] = gnn_afrag(Xs, rt, ktq, l16); }
#pragma unroll
    for (int c = 0; c < 2; ++c) {
      int ct = wave * 2 + c;
      bf16x8 bZT = gnn_bfrag(pkRZ, 8 + ct, kt,     8, lane);
      bf16x8 bZX = gnn_bfrag(pkRZ, 8 + ct, kt + 4, 8, lane);
#pragma unroll
      for (int rt = 0; rt < 4; ++rt) {
        zz[rt][c] = __builtin_amdgcn_mfma_f32_16x16x32_bf16(tf[rt], bZT, zz[rt][c], 0, 0, 0);
        zz[rt][c] = __builtin_amdgcn_mfma_f32_16x16x32_bf16(xf[rt], bZX, zz[rt][c], 0, 0, 0);
      }
    }
  }

  // combine + store (h from Xs LDS)
#pragma unroll
  for (int rt = 0; rt < 4; ++rt)
#pragma unroll
    for (int c = 0; c < 2; ++c) {
      int col = (wave * 2 + c) * 16 + l16;
      int rowl = rt * 16 + quad * 4;
#pragma unroll
      for (int r = 0; r < 4; ++r) {
        float z = gnn_sig(zz[rt][c][r] + bzz[c]);
        float h = gnn_lds_get(Xs, rowl + r, col);
        float v = (1.f - z) * ai[rt][c][r] + z * h;
        if (RELU) v = fmaxf(v, 0.f);
        Y[(row0 + rowl + r) * H + col] = gnn_f2bf(v);
      }
    }
}

// ============================================================================
// FUSED g1+g2: C = (relu(A@pk1+b1))@pk2 + b2  (both K=128, N=128)
// intermediate re-staged through LDS in A-layout.
// ============================================================================
__global__ __launch_bounds__(256) void gnn_g1g2(const u16* __restrict__ A,
                                                const u16* __restrict__ pk1, const float* __restrict__ b1,
                                                const u16* __restrict__ pk2, const float* __restrict__ b2,
                                                u16* __restrict__ C) {
  __shared__ u16 As[64 * 128];
  __shared__ u16 Ys[64 * 128];
  const int tid = threadIdx.x;
  const int lane = tid & 63, wave = tid >> 6;
  const int quad = lane >> 4, l16 = lane & 15;
  const long row0 = (long)blockIdx.x * 64;
  gnn_stage_bf<128>(A, row0, As, tid);
  __syncthreads();

  f32x4 zero4 = {0.f, 0.f, 0.f, 0.f};
  f32x4 acc[4][2];
#pragma unroll
  for (int rt = 0; rt < 4; ++rt)
#pragma unroll
    for (int ct = 0; ct < 2; ++ct) acc[rt][ct] = zero4;
#pragma unroll
  for (int kt = 0; kt < 4; ++kt) {
    int ktq = kt * 4 + quad;
    bf16x8 af[4];
#pragma unroll
    for (int rt = 0; rt < 4; ++rt) af[rt] = gnn_afrag(As, rt, ktq, l16);
#pragma unroll
    for (int ct = 0; ct < 2; ++ct) {
      bf16x8 bf = gnn_bfrag(pk1, wave * 2 + ct, kt, 4, lane);
#pragma unroll
      for (int rt = 0; rt < 4; ++rt)
        acc[rt][ct] = __builtin_amdgcn_mfma_f32_16x16x32_bf16(af[rt], bf, acc[rt][ct], 0, 0, 0);
    }
  }
#pragma unroll
  for (int ct = 0; ct < 2; ++ct) {
    int col = (wave * 2 + ct) * 16 + l16;
    float bv = b1[col];
#pragma unroll
    for (int rt = 0; rt < 4; ++rt) {
      int rowl = rt * 16 + quad * 4;
#pragma unroll
      for (int r = 0; r < 4; ++r)
        gnn_lds_put(Ys, rowl + r, col, fmaxf(acc[rt][ct][r] + bv, 0.f));
    }
  }
  __syncthreads();

  f32x4 acc2[4][2];
#pragma unroll
  for (int rt = 0; rt < 4; ++rt)
#pragma unroll
    for (int ct = 0; ct < 2; ++ct) acc2[rt][ct] = zero4;
#pragma unroll
  for (int kt = 0; kt < 4; ++kt) {
    int ktq = kt * 4 + quad;
    bf16x8 af[4];
#pragma unroll
    for (int rt = 0; rt < 4; ++rt) af[rt] = gnn_afrag(Ys, rt, ktq, l16);
#pragma unroll
    for (int ct = 0; ct < 2; ++ct) {
      bf16x8 bf = gnn_bfrag(pk2, wave * 2 + ct, kt, 4, lane);
#pragma unroll
      for (int rt = 0; rt < 4; ++rt)
        acc2[rt][ct] = __builtin_amdgcn_mfma_f32_16x16x32_bf16(af[rt], bf, acc2[rt][ct], 0, 0, 0);
    }
  }
#pragma unroll
  for (int ct = 0; ct < 2; ++ct) {
    int col = (wave * 2 + ct) * 16 + l16;
    float bv = b2[col];
#pragma unroll
    for (int rt = 0; rt < 4; ++rt) {
      long row = row0 + rt * 16 + quad * 4;
#pragma unroll
      for (int r = 0; r < 4; ++r)
        C[(row + r) * H + col] = gnn_f2bf(acc2[rt][ct][r] + bv);
    }
  }
}

// ============================================================================
// FUSED l1+l2: u2 = relu( relu(A@pk1 + gb[graph])@pk2 + b2 )
// l1: K=128,N=256 (per-graph bias gb); l2: K=256,N=128.
// ============================================================================
__global__ __launch_bounds__(256) void gnn_l1l2(const u16* __restrict__ A,
                                                const u16* __restrict__ pk1, const float* __restrict__ gb,
                                                const u16* __restrict__ pk2, const float* __restrict__ b2,
                                                u16* __restrict__ C) {
  __shared__ u16 As[64 * 128];   // 16KB
  __shared__ u16 Us[64 * 256];   // 32KB
  const int tid = threadIdx.x;
  const int lane = tid & 63, wave = tid >> 6;
  const int quad = lane >> 4, l16 = lane & 15;
  const long row0 = (long)blockIdx.x * 64;
  gnn_stage_bf<128>(A, row0, As, tid);
  __syncthreads();

  f32x4 zero4 = {0.f, 0.f, 0.f, 0.f};
  {
    f32x4 acc[4][4];
#pragma unroll
    for (int rt = 0; rt < 4; ++rt)
#pragma unroll
      for (int ct = 0; ct < 4; ++ct) acc[rt][ct] = zero4;
#pragma unroll
    for (int kt = 0; kt < 4; ++kt) {
      int ktq = kt * 4 + quad;
      bf16x8 af[4];
#pragma unroll
      for (int rt = 0; rt < 4; ++rt) af[rt] = gnn_afrag(As, rt, ktq, l16);
#pragma unroll
      for (int ct = 0; ct < 4; ++ct) {
        bf16x8 bf = gnn_bfrag(pk1, wave * 4 + ct, kt, 4, lane);
#pragma unroll
        for (int rt = 0; rt < 4; ++rt)
          acc[rt][ct] = __builtin_amdgcn_mfma_f32_16x16x32_bf16(af[rt], bf, acc[rt][ct], 0, 0, 0);
      }
    }
    const float* bp = gb + (row0 >> 12) * 256;
#pragma unroll
    for (int ct = 0; ct < 4; ++ct) {
      int col = (wave * 4 + ct) * 16 + l16;
      float bv = bp[col];
#pragma unroll
      for (int rt = 0; rt < 4; ++rt) {
        int rowl = rt * 16 + quad * 4;
#pragma unroll
        for (int r = 0; r < 4; ++r)
          gnn_lds_put(Us, rowl + r, col, fmaxf(acc[rt][ct][r] + bv, 0.f));
      }
    }
  }
  __syncthreads();

  f32x4 acc2[4][2];
#pragma unroll
  for (int rt = 0; rt < 4; ++rt)
#pragma unroll
    for (int ct = 0; ct < 2; ++ct) acc2[rt][ct] = zero4;
#pragma unroll
  for (int kt = 0; kt < 8; ++kt) {
    int ktq = kt * 4 + quad;
    bf16x8 af[4];
#pragma unroll
    for (int rt = 0; rt < 4; ++rt) af[rt] = gnn_afrag(Us, rt, ktq, l16);
#pragma unroll
    for (int ct = 0; ct < 2; ++ct) {
      bf16x8 bf = gnn_bfrag(pk2, wave * 2 + ct, kt, 8, lane);
#pragma unroll
      for (int rt = 0; rt < 4; ++rt)
        acc2[rt][ct] = __builtin_amdgcn_mfma_f32_16x16x32_bf16(af[rt], bf, acc2[rt][ct], 0, 0, 0);
    }
  }
#pragma unroll
  for (int ct = 0; ct < 2; ++ct) {
    int col = (wave * 2 + ct) * 16 + l16;
    float bv = b2[col];
#pragma unroll
    for (int rt = 0; rt < 4; ++rt) {
      long row = row0 + rt * 16 + quad * 4;
#pragma unroll
      for (int r = 0; r < 4; ++r)
        C[(row + r) * H + col] = gnn_f2bf(fmaxf(acc2[rt][ct][r] + bv, 0.f));
    }
  }
}

// ============================================================================
// fp32-input GEMM (emb1, K=16), bf16 output
// ============================================================================
#define GFMA(i, av) \
  acc[(i)*4+0] = fmaf((av), wv.x, acc[(i)*4+0]); \
  acc[(i)*4+1] = fmaf((av), wv.y, acc[(i)*4+1]); \
  acc[(i)*4+2] = fmaf((av), wv.z, acc[(i)*4+2]); \
  acc[(i)*4+3] = fmaf((av), wv.w, acc[(i)*4+3]);

__global__ __launch_bounds__(256) void gnn_gemm16(const float* __restrict__ A, const float* __restrict__ W,
                                                  const float* __restrict__ bias, u16* __restrict__ C,
                                                  int OUT) {
  const int K = 16;
  __shared__ float AsT[16][68];
  __shared__ float Ws[16][68];
  const int tid = threadIdx.x;
  const int tx = tid & 15, ty = tid >> 4;
  const long row0 = (long)blockIdx.y * 64;
  const int col0 = blockIdx.x * 64;
  const int lr  = tid >> 2;
  const int lk4 = (tid & 3) * 4;
  const int wk  = tid >> 4;
  const int wj4 = (tid & 15) * 4;
  float acc[16];
#pragma unroll
  for (int i = 0; i < 16; ++i) acc[i] = 0.f;

  {
    float4 a = *(const float4*)(A + (row0 + lr) * K + lk4);
    float4 w = *(const float4*)(W + (long)wk * OUT + col0 + wj4);
    AsT[lk4 + 0][lr] = a.x; AsT[lk4 + 1][lr] = a.y; AsT[lk4 + 2][lr] = a.z; AsT[lk4 + 3][lr] = a.w;
    *(float4*)(&Ws[wk][wj4]) = w;
    __syncthreads();
#pragma unroll
    for (int k = 0; k < 16; ++k) {
      float4 av = *(const float4*)(&AsT[k][ty * 4]);
      float4 wv = *(const float4*)(&Ws[k][tx * 4]);
      GFMA(0, av.x) GFMA(1, av.y) GFMA(2, av.z) GFMA(3, av.w)
    }
  }
#pragma unroll
  for (int i = 0; i < 4; ++i) {
    long row = row0 + ty * 4 + i;
    int j = col0 + tx * 4;
    float4 o;
    o.x = fmaxf(acc[i * 4 + 0] + bias[j + 0], 0.f);
    o.y = fmaxf(acc[i * 4 + 1] + bias[j + 1], 0.f);
    o.z = fmaxf(acc[i * 4 + 2] + bias[j + 2], 0.f);
    o.w = fmaxf(acc[i * 4 + 3] + bias[j + 3], 0.f);
    uint2 st;
    st.x = gnn_pack2bf(o.x, o.y);
    st.y = gnn_pack2bf(o.z, o.w);
    *(uint2*)(C + row * OUT + j) = st;
  }
}
#undef GFMA

// ============================================================================
// head: pool, per-graph bias, item-value init, final bound reduction
// ============================================================================
__global__ __launch_bounds__(128) void gnn_pool(const u16* __restrict__ X3, float* __restrict__ ge) {
  int b = blockIdx.x >> 3, chunk = blockIdx.x & 7, t = threadIdx.x;
  long base = ((long)b * PP + chunk * 512) * H;
  float acc = 0.f;
  for (int p = 0; p < 512; ++p) acc += gnn_bf2f(X3[base + (long)p * H + t]);
  atomicAdd(&ge[b * H + t], acc);
}

__global__ __launch_bounds__(256) void gnn_gbias(const float* __restrict__ ge, const float* __restrict__ Wl1b,
                                                 const float* __restrict__ bl1, float* __restrict__ gb) {
  __shared__ float g[128];
  int b = blockIdx.x, t = threadIdx.x;
  if (t < 128) g[t] = ge[b * H + t] * (1.f / 4096.f);
  __syncthreads();
  float acc = bl1[t];
  for (int k = 0; k < 128; ++k) acc = fmaf(g[k], Wl1b[k * 256 + t], acc);
  gb[b * 256 + t] = acc;
}

__global__ __launch_bounds__(256) void gnn_item(const float* __restrict__ iv, const int* __restrict__ vvs,
                                                float* __restrict__ out) {
  __shared__ float s[256];
  int b = blockIdx.x, t = threadIdx.x;
  float v = iv[b * 256 + t] * (float)vvs[(long)b * PP + t];
  s[t] = v; __syncthreads();
  for (int off = 128; off > 0; off >>= 1) {
    if (t < off) s[t] += s[t + off];
    __syncthreads();
  }
  if (t == 0) out[b] = s[0];
}

__global__ __launch_bounds__(256) void gnn_bound(const u16* __restrict__ U2, const float* __restrict__ wl3,
                                                 const float* __restrict__ bl3, const int* __restrict__ vvs,
                                                 float* __restrict__ out) {
  int tid = threadIdx.x;
  int wave = tid >> 6, lane = tid & 63;
  int b = blockIdx.x >> 6;
  long node0 = (long)blockIdx.x * 64 + wave * 16;
  float w0 = wl3[lane * 2], w1 = wl3[lane * 2 + 1];
  float bl = bl3[0];
  float acc = 0.f;
  for (int i = 0; i < 16; ++i) {
    long node = node0 + i;
    unsigned pv = *(const unsigned*)(U2 + node * H + lane * 2);
    union { unsigned u; float f; } lo, hi;
    lo.u = pv << 16; hi.u = pv & 0xFFFF0000u;
    float p = lo.f * w0 + hi.f * w1;
#pragma unroll
    for (int off = 32; off > 0; off >>= 1) p += __shfl_down(p, off);
    if (lane == 0) {
      int pp = (int)(node & (PP - 1));
      int m = pp >> 8, n = pp & 255;
      if (m != 0) {
        float dx = (float)(vvs[((long)b << 12) + n] - vvs[((long)b << 12) + pp]);
        acc += (p + bl) * dx;
      }
    }
  }
  __shared__ float s[4];
  if (lane == 0) s[wave] = acc;
  __syncthreads();
  if (tid == 0) atomicAdd(&out[b], s[0] + s[1] + s[2] + s[3]);
}

// ============================================================================
extern "C" void kernel_launch(void* const* d_in, const int* in_sizes, int n_in,
                              void* d_out, int out_size, void* d_ws, size_t ws_size,
                              hipStream_t stream) {
  const float* G      = (const float*)d_in[0];
  const int*   ei     = (const int*)d_in[1];
  const int*   esrc   = ei;
  const int*   edst   = ei + EDGES;
  const float* ew     = (const float*)d_in[2];
  const int*   vvs    = (const int*)d_in[4];
  const float* iv     = (const float*)d_in[5];
  const float* W_emb1 = (const float*)d_in[6];
  const float* b_emb1 = (const float*)d_in[7];
  const float* W_emb2 = (const float*)d_in[8];
  const float* b_emb2 = (const float*)d_in[9];
  const float* c1_W   = (const float*)d_in[10];
  const float* c1_wi  = (const float*)d_in[11];
  const float* c1_wh  = (const float*)d_in[12];
  const float* c1_bi  = (const float*)d_in[13];
  const float* c1_bh  = (const float*)d_in[14];
  const float* c2_W   = (const float*)d_in[15];
  const float* c2_wi  = (const float*)d_in[16];
  const float* c2_wh  = (const float*)d_in[17];
  const float* c2_bi  = (const float*)d_in[18];
  const float* c2_bh  = (const float*)d_in[19];
  const float* W_g1   = (const float*)d_in[20];
  const float* b_g1   = (const float*)d_in[21];
  const float* W_g2   = (const float*)d_in[22];
  const float* b_g2   = (const float*)d_in[23];
  const float* W_l1   = (const float*)d_in[24];
  const float* b_l1   = (const float*)d_in[25];
  const float* W_l2   = (const float*)d_in[26];
  const float* b_l2   = (const float*)d_in[27];
  const float* W_l3   = (const float*)d_in[28];
  const float* b_l3   = (const float*)d_in[29];
  float* out = (float*)d_out;
  (void)in_sizes; (void)n_in; (void)out_size; (void)ws_size;

  // ---- workspace carve (~135 MiB) ----
  char* wsb = (char*)d_ws;
  size_t off = 0;
  auto carve = [&](size_t bytes) -> char* {
    char* p = wsb + off;
    off += (bytes + 255) & ~(size_t)255;
    return p;
  };
  u16*   xa     = (u16*)carve(sizeof(u16) * (size_t)NODES * H);
  u16*   xc     = (u16*)carve(sizeof(u16) * (size_t)NODES * H);
  u16*   tb     = (u16*)carve(sizeof(u16) * (size_t)NODES * H);
  float* Wc     = (float*)carve(sizeof(float) * 4 * H * 384);
  float* whT    = (float*)carve(sizeof(float) * 2 * H * 384);
  u16*   pk     = (u16*)carve(sizeof(u16) * 507904);
  int*   rowptr = (int*)carve(sizeof(int) * (NODES + 1));
  int*   pcur   = (int*)carve(sizeof(int) * 128);
  int*   pbase  = (int*)carve(sizeof(int) * 128);
  uint2* stage  = (uint2*)carve(sizeof(uint2) * (size_t)128 * CAPP);
  unsigned* epack = (unsigned*)carve(sizeof(unsigned) * EDGES);
  float* ge     = (float*)carve(sizeof(float) * NB * H);
  float* gb     = (float*)carve(sizeof(float) * NB * 256);

  u16* pkRZ[4]; u16* pkAI[4]; u16* pkAH[4];
  for (int l = 0; l < 4; ++l) {
    pkRZ[l] = pk + (long)l * LYRE;
    pkAI[l] = pk + (long)l * LYRE + RZE;
    pkAH[l] = pk + (long)l * LYRE + RZE + AIE;
  }
  u16* pe2 = pk + 4 * LYRE;
  u16* pg1 = pe2 + 16384;
  u16* pg2 = pe2 + 32768;
  u16* pl1 = pe2 + 49152;
  u16* pl2 = pe2 + 81920;

  // ---- CSR build ----
  hipMemsetAsync(ge, 0, sizeof(float) * NB * H, stream);
  gnn_pinit<<<1, 128, 0, stream>>>(pcur);
  gnn_bin1<<<B1_BLOCKS, 256, 0, stream>>>(esrc, edst, ew, pcur, stage);
  gnn_pscan<<<1, 128, 0, stream>>>(pcur, pbase);
  gnn_bin2<<<128, 256, 0, stream>>>(stage, pcur, pbase, rowptr, epack);

  // ---- weight prep + pack (consolidated) ----
  gnn_prep_wc_all<<<512, 384, 0, stream>>>(c1_W, c1_wi, c2_W, c2_wi, Wc);
  gnn_prep_whT<<<256, 384, 0, stream>>>(c1_wh, c2_wh, whT);
  gnn_pack_layers<<<768, 64, 0, stream>>>(Wc, whT, pk);
  gnn_pack_misc<<<224, 64, 0, stream>>>(W_emb2, W_g1, W_g2, W_l1, W_l2, pk);

  // ---- embeddings: G -> xa -> xc ----
  gnn_gemm16<<<dim3(2, NODES / 64), 256, 0, stream>>>(G, W_emb1, b_emb1, xa, 128);
  gnn_mgemm<128, 128, 1><<<NODES / 64, 256, 0, stream>>>(xa, pe2, b_emb2, xc);

  // ---- conv1 + conv2 (fused agg+GRU) ----
  gnn_aggru<0><<<NODES / 64, 256, 0, stream>>>(xc, rowptr, epack, pkRZ[0], pkAI[0], pkAH[0], c1_bi, c1_bh, xa);
  gnn_aggru<1><<<NODES / 64, 256, 0, stream>>>(xa, rowptr, epack, pkRZ[1], pkAI[1], pkAH[1], c1_bi, c1_bh, xc);
  gnn_aggru<0><<<NODES / 64, 256, 0, stream>>>(xc, rowptr, epack, pkRZ[2], pkAI[2], pkAH[2], c2_bi, c2_bh, xa);
  gnn_aggru<1><<<NODES / 64, 256, 0, stream>>>(xa, rowptr, epack, pkRZ[3], pkAI[3], pkAH[3], c2_bi, c2_bh, xc);

  // ---- head GEMMs fused: xc -> tb (x3) ----
  gnn_g1g2<<<NODES / 64, 256, 0, stream>>>(xc, pg1, b_g1, pg2, b_g2, tb);

  // ---- pool + per-graph bias (folds ge @ W_l1[128:] + b_l1) ----
  gnn_pool<<<NB * 8, 128, 0, stream>>>(tb, ge);
  gnn_gbias<<<NB, 256, 0, stream>>>(ge, W_l1 + 128 * 256, b_l1, gb);

  // ---- MLP fused l1+l2: tb -> xa (u2) ----
  gnn_l1l2<<<NODES / 64, 256, 0, stream>>>(tb, pl1, gb, pl2, b_l2, xa);

  // ---- bound ----
  gnn_item<<<NB, 256, 0, stream>>>(iv, vvs, out);
  gnn_bound<<<NODES / 64, 256, 0, stream>>>(xa, W_l3, b_l3, vvs, out);
}

// Round 10
// 923.992 us; speedup vs baseline: 1.8184x; 1.8184x over previous
//
#include <hip/hip_runtime.h>

#define NODES   131072
#define EDGES   2097152
#define H       128
#define NB      32        // graphs
#define PP      4096      // nodes per problem graph

typedef short bf16x8 __attribute__((ext_vector_type(8)));
typedef float f32x4  __attribute__((ext_vector_type(4)));
typedef unsigned short u16;

// packed-weight element offsets
#define RZE 65536
#define AIE 16384
#define AHE 16384
#define LYRE (RZE + AIE + AHE)   // 98304 per conv layer

// ============================================================================
// CSR build, histogram-free. Partition p = dst>>10, fixed slab CAPP; bin1
// stages with contiguous-run writes; bin2 builds rowptr slice via LDS
// hist+scan and scatters (one block owns each 64KB epack slice).
// ============================================================================
#define CAPP 18432

__global__ __launch_bounds__(128) void gnn_pinit(int* __restrict__ pcur) {
  pcur[threadIdx.x] = threadIdx.x * CAPP;
}

// Staged record: .x = src(17b)<<15 | round(ew*32768), .y = dst
#define B1_BLOCKS 256
#define B1_TILES  4
__global__ __launch_bounds__(256) void gnn_bin1(const int* __restrict__ src, const int* __restrict__ dst,
                                                const float* __restrict__ ew, int* __restrict__ pcur,
                                                uint2* __restrict__ stage) {
  __shared__ int hist[128];
  __shared__ int pbase[128];
  const int tid = threadIdx.x;
  for (int t = 0; t < B1_TILES; ++t) {
    if (tid < 128) hist[tid] = 0;
    __syncthreads();
    const int ebase = blockIdx.x * (B1_TILES * 2048) + t * 2048;
    int parts[8], ranks[8];
    uint2 recs[8];
#pragma unroll
    for (int i = 0; i < 8; ++i) {
      int e = ebase + i * 256 + tid;
      int d = dst[e];
      int s = src[e];
      float w = ew[e];
      int wq = (int)fminf(w * 32768.f + 0.5f, 32767.f);
      parts[i] = d >> 10;
      recs[i].x = ((unsigned)s << 15) | (unsigned)wq;
      recs[i].y = (unsigned)d;
      ranks[i] = atomicAdd(&hist[parts[i]], 1);
    }
    __syncthreads();
    if (tid < 128) {
      int c = hist[tid];
      pbase[tid] = c ? atomicAdd(&pcur[tid], c) : 0;
    }
    __syncthreads();
#pragma unroll
    for (int i = 0; i < 8; ++i)
      stage[pbase[parts[i]] + ranks[i]] = recs[i];
    __syncthreads();
  }
}

__global__ __launch_bounds__(128) void gnn_pscan(const int* __restrict__ pcur, int* __restrict__ pbase) {
  __shared__ int s[128];
  int t = threadIdx.x;
  int v = pcur[t] - t * CAPP;
  s[t] = v; __syncthreads();
  for (int o = 1; o < 128; o <<= 1) {
    int u = (t >= o) ? s[t - o] : 0;
    __syncthreads();
    s[t] += u;
    __syncthreads();
  }
  pbase[t] = s[t] - v;
}

__global__ __launch_bounds__(256) void gnn_bin2(const uint2* __restrict__ stage,
                                                const int* __restrict__ pcur,
                                                const int* __restrict__ pbase,
                                                int* __restrict__ rowptr,
                                                unsigned* __restrict__ epack) {
  __shared__ int h[1024];
  __shared__ int ws[256];
  const int tid = threadIdx.x;
  const int p = blockIdx.x;
  const int node0 = p << 10;
  const int s0 = p * CAPP;
  const int cnt = pcur[p] - s0;
  const int gbase = pbase[p];
#pragma unroll
  for (int i = 0; i < 4; ++i) h[i * 256 + tid] = 0;
  __syncthreads();
  for (int r = tid; r < cnt; r += 256)
    atomicAdd(&h[(int)stage[s0 + r].y - node0], 1);
  __syncthreads();
  int a0 = h[tid * 4 + 0], a1 = h[tid * 4 + 1], a2 = h[tid * 4 + 2], a3 = h[tid * 4 + 3];
  int s1 = a0 + a1, s2 = s1 + a2, s3 = s2 + a3;
  ws[tid] = s3;
  __syncthreads();
  for (int o = 1; o < 256; o <<= 1) {
    int u = (tid >= o) ? ws[tid - o] : 0;
    __syncthreads();
    ws[tid] += u;
    __syncthreads();
  }
  int eb = gbase + (tid ? ws[tid - 1] : 0);
  int4 rp;
  rp.x = eb; rp.y = eb + a0; rp.z = eb + s1; rp.w = eb + s2;
  *(int4*)(rowptr + node0 + tid * 4) = rp;
  h[tid * 4 + 0] = rp.x; h[tid * 4 + 1] = rp.y; h[tid * 4 + 2] = rp.z; h[tid * 4 + 3] = rp.w;
  if (p == 127 && tid == 255) rowptr[NODES] = EDGES;
  __syncthreads();
  for (int r = tid; r < cnt; r += 256) {
    uint2 q = stage[s0 + r];
    int pos = atomicAdd(&h[(int)q.y - node0], 1);
    epack[pos] = q.x;
  }
}

// ============================================================================
// bf16 helpers
// ============================================================================
__device__ __forceinline__ unsigned gnn_pack2bf(float a, float b) {
  union { float f; unsigned u; } x, y; x.f = a; y.f = b;
  unsigned ua = (x.u + 0x7FFFu + ((x.u >> 16) & 1u)) >> 16;
  unsigned ub = (y.u + 0x7FFFu + ((y.u >> 16) & 1u)) >> 16;
  return ua | (ub << 16);
}

__device__ __forceinline__ u16 gnn_f2bf(float a) {
  union { float f; unsigned u; } x; x.f = a;
  return (u16)((x.u + 0x7FFFu + ((x.u >> 16) & 1u)) >> 16);
}

__device__ __forceinline__ float gnn_bf2f(u16 h) {
  union { unsigned u; float f; } x; x.u = ((unsigned)h) << 16; return x.f;
}

__device__ __forceinline__ float gnn_sig(float x)  { return 1.f / (1.f + __expf(-x)); }
__device__ __forceinline__ float gnn_tanh(float x) { return 1.f - 2.f / (1.f + __expf(2.f * x)); }

// ============================================================================
// STANDALONE agg (round-8 proven: 28 VGPR, 75% occupancy, latency-bound
// gather needs waves-in-flight — round 9 showed fusing it into the
// register-heavy GRU chokes it to 6% occupancy / 4.4x slower).
// One wave per node; lane covers cols {2*lane,2*lane+1}; 16-deep pipeline.
// ============================================================================
__device__ __forceinline__ void gnn_agg_edge(const u16* __restrict__ X, unsigned q, int lane,
                                             float& a0, float& a1) {
  unsigned pv = *(const unsigned*)(X + (long)(q >> 15) * H + lane * 2);
  float w = (float)(q & 0x7FFFu) * (1.f / 32768.f);
  union { unsigned u; float f; } lo, hi;
  lo.u = pv << 16; hi.u = pv & 0xFFFF0000u;
  a0 = fmaf(w, lo.f, a0);
  a1 = fmaf(w, hi.f, a1);
}

__global__ __launch_bounds__(256) void gnn_agg(const u16* __restrict__ X, const int* __restrict__ rowptr,
                                               const unsigned* __restrict__ epack,
                                               u16* __restrict__ T) {
  int wave = threadIdx.x >> 6, lane = threadIdx.x & 63;
  long node = (long)blockIdx.x * 4 + wave;
  int e0 = rowptr[node], e1 = rowptr[node + 1];
  float a0 = 0.f, a1 = 0.f;
  int e = e0;
  for (; e + 16 <= e1; e += 16) {
    unsigned q[16];
#pragma unroll
    for (int j = 0; j < 16; ++j) q[j] = epack[e + j];
    unsigned p[16];
#pragma unroll
    for (int j = 0; j < 16; ++j) p[j] = *(const unsigned*)(X + (long)(q[j] >> 15) * H + lane * 2);
#pragma unroll
    for (int j = 0; j < 16; ++j) {
      float w = (float)(q[j] & 0x7FFFu) * (1.f / 32768.f);
      union { unsigned u; float f; } lo, hi;
      lo.u = p[j] << 16; hi.u = p[j] & 0xFFFF0000u;
      a0 = fmaf(w, lo.f, a0);
      a1 = fmaf(w, hi.f, a1);
    }
  }
  if (e + 8 <= e1) {
    unsigned q[8];
#pragma unroll
    for (int j = 0; j < 8; ++j) q[j] = epack[e + j];
    unsigned p[8];
#pragma unroll
    for (int j = 0; j < 8; ++j) p[j] = *(const unsigned*)(X + (long)(q[j] >> 15) * H + lane * 2);
#pragma unroll
    for (int j = 0; j < 8; ++j) {
      float w = (float)(q[j] & 0x7FFFu) * (1.f / 32768.f);
      union { unsigned u; float f; } lo, hi;
      lo.u = p[j] << 16; hi.u = p[j] & 0xFFFF0000u;
      a0 = fmaf(w, lo.f, a0);
      a1 = fmaf(w, hi.f, a1);
    }
    e += 8;
  }
  if (e + 4 <= e1) {
    unsigned q[4];
#pragma unroll
    for (int j = 0; j < 4; ++j) q[j] = epack[e + j];
#pragma unroll
    for (int j = 0; j < 4; ++j) gnn_agg_edge(X, q[j], lane, a0, a1);
    e += 4;
  }
  for (; e < e1; ++e) gnn_agg_edge(X, epack[e], lane, a0, a1);
  *(unsigned*)(T + node * H + lane * 2) = gnn_pack2bf(a0, a1);
}

// ============================================================================
// weight prep (consolidated): Wc[l] = W[l] @ wi.T ; whT = wh.T
// ============================================================================
__global__ __launch_bounds__(384) void gnn_prep_wc_all(const float* __restrict__ c1W, const float* __restrict__ c1wi,
                                                       const float* __restrict__ c2W, const float* __restrict__ c2wi,
                                                       float* __restrict__ Wc) {
  __shared__ float wrow[128];
  int l = blockIdx.x >> 7, k = blockIdx.x & 127, j = threadIdx.x;
  const float* Wl = (l < 2 ? c1W : c2W) + (l & 1) * 128 * 128;
  const float* wi = l < 2 ? c1wi : c2wi;
  if (j < 128) wrow[j] = Wl[k * 128 + j];
  __syncthreads();
  float acc = 0.f;
  for (int m = 0; m < 128; ++m) acc = fmaf(wrow[m], wi[j * 128 + m], acc);
  Wc[(long)l * 49152 + k * 384 + j] = acc;
}

__global__ __launch_bounds__(384) void gnn_prep_whT(const float* __restrict__ wh1, const float* __restrict__ wh2,
                                                    float* __restrict__ whT) {
  int c = blockIdx.x >> 7, k = blockIdx.x & 127, j = threadIdx.x;
  const float* wh = c ? wh2 : wh1;
  whT[((long)c * 128 + k) * 384 + j] = wh[j * 128 + k];
}

// ============================================================================
// MFMA fragment plumbing
// A-frag (16x16x32): A[m=lane&15][k=(lane>>4)*8+j]; B[k][n=lane&15]
// C/D: col=lane&15, row=(lane>>4)*4+reg
// LDS A staging: slot(ktq,row) = ktq*64 + (row ^ (ktq&7)), 16B/slot
// ============================================================================
template<int K>
__device__ __forceinline__ void gnn_stage_bf(const u16* __restrict__ A, long row0,
                                             u16* lds, int tid) {
  constexpr int CH = K / 8;
#pragma unroll
  for (int it = 0; it < (64 * CH) / 256; ++it) {
    int c = it * 256 + tid;
    int row = c / CH, ktq = c % CH;
    uint4 v = *(const uint4*)(A + (row0 + row) * K + ktq * 8);
    int slot = ktq * 64 + (row ^ (ktq & 7));
    *(uint4*)(lds + slot * 8) = v;
  }
}

__device__ __forceinline__ bf16x8 gnn_afrag(const u16* lds, int rt, int ktq, int l16) {
  int slot = ktq * 64 + ((rt * 16 + l16) ^ (ktq & 7));
  return *(const bf16x8*)(lds + slot * 8);
}

__device__ __forceinline__ bf16x8 gnn_bfrag(const u16* __restrict__ pk,
                                            int ct, int kt, int KT, int lane) {
  return *(const bf16x8*)(pk + (((long)(ct * KT + kt)) * 64 + lane) * 8);
}

// scalar store of a C-layout element into A-layout LDS (for GEMM chaining)
__device__ __forceinline__ void gnn_lds_put(u16* lds, int row, int col, float v) {
  int kq = col >> 3, of = col & 7;
  lds[(kq * 64 + (row ^ (kq & 7))) * 8 + of] = gnn_f2bf(v);
}

__device__ __forceinline__ float gnn_lds_get(const u16* lds, int row, int col) {
  int kq = col >> 3, of = col & 7;
  return gnn_bf2f(lds[(kq * 64 + (row ^ (kq & 7))) * 8 + of]);
}

// ============================================================================
// weight packing to MFMA B-frag bf16 (consolidated kernels)
// ============================================================================
__device__ __forceinline__ void gnn_pack_body(const float* __restrict__ W0, const float* __restrict__ W1,
                                              int ksplit, int LD, int coff, int KT, int b, int lane,
                                              u16* __restrict__ dst) {
  int kt = b % KT, ct = b / KT;
  int col = ct * 16 + (lane & 15) + coff;
  int kb = kt * 32 + ((lane >> 4) & 3) * 8;
  u16 h[8];
#pragma unroll
  for (int j = 0; j < 8; ++j) {
    int k = kb + j;
    float v = (k < ksplit) ? W0[(long)k * LD + col] : W1[(long)(k - ksplit) * LD + col];
    h[j] = gnn_f2bf(v);
  }
  uint4 o;
  o.x = (unsigned)h[0] | ((unsigned)h[1] << 16);
  o.y = (unsigned)h[2] | ((unsigned)h[3] << 16);
  o.z = (unsigned)h[4] | ((unsigned)h[5] << 16);
  o.w = (unsigned)h[6] | ((unsigned)h[7] << 16);
  ((uint4*)dst)[(long)b * 64 + lane] = o;
}

// 4 conv layers x (rz 128 + ai 32 + ah 32) = 768 blocks
__global__ __launch_bounds__(64) void gnn_pack_layers(const float* __restrict__ Wc, const float* __restrict__ whT,
                                                      u16* __restrict__ pk) {
  int l = blockIdx.x / 192, r = blockIdx.x % 192;
  int lane = threadIdx.x;
  const float* Wcl = Wc + (long)l * 49152;
  const float* whl = whT + (long)(l >> 1) * 49152;
  u16* base = pk + (long)l * LYRE;
  if (r < 128)      gnn_pack_body(Wcl, whl, 128, 384, 0,   8, r,       lane, base);
  else if (r < 160) gnn_pack_body(Wcl, Wcl, 128, 384, 256, 4, r - 128, lane, base + RZE);
  else              gnn_pack_body(whl, whl, 128, 384, 256, 4, r - 160, lane, base + RZE + AIE);
}

// pe2(32) pg1(32) pg2(32) pl1(64) pl2(64) = 224 blocks
__global__ __launch_bounds__(64) void gnn_pack_misc(const float* __restrict__ We2, const float* __restrict__ Wg1,
                                                    const float* __restrict__ Wg2, const float* __restrict__ Wl1,
                                                    const float* __restrict__ Wl2, u16* __restrict__ pk) {
  int b = blockIdx.x, lane = threadIdx.x;
  u16* pe2 = pk + 4 * LYRE;
  if (b < 32)       gnn_pack_body(We2, We2, 128, 128, 0, 4, b,       lane, pe2);
  else if (b < 64)  gnn_pack_body(Wg1, Wg1, 128, 128, 0, 4, b - 32,  lane, pe2 + 16384);
  else if (b < 96)  gnn_pack_body(Wg2, Wg2, 128, 128, 0, 4, b - 64,  lane, pe2 + 32768);
  else if (b < 160) gnn_pack_body(Wl1, Wl1, 128, 256, 0, 4, b - 96,  lane, pe2 + 49152);
  else              gnn_pack_body(Wl2, Wl2, 256, 128, 0, 8, b - 160, lane, pe2 + 81920);
}

// ============================================================================
// MFMA GEMM (emb2): C = relu(A@Wpk + bias), 64-row blocks
// ============================================================================
template<int K, int N, int ACT>
__global__ __launch_bounds__(256) void gnn_mgemm(const u16* __restrict__ A,
                                                 const u16* __restrict__ pk,
                                                 const float* __restrict__ bias,
                                                 u16* __restrict__ C) {
  constexpr int KT = K / 32;
  constexpr int CT = N / 64;
  __shared__ u16 As[64 * K];
  const int tid = threadIdx.x;
  const int lane = tid & 63, wave = tid >> 6;
  const int quad = lane >> 4, l16 = lane & 15;
  const long row0 = (long)blockIdx.x * 64;
  gnn_stage_bf<K>(A, row0, As, tid);
  __syncthreads();

  f32x4 zero4 = {0.f, 0.f, 0.f, 0.f};
  f32x4 acc[4][CT];
#pragma unroll
  for (int rt = 0; rt < 4; ++rt)
#pragma unroll
    for (int ct = 0; ct < CT; ++ct) acc[rt][ct] = zero4;

#pragma unroll
  for (int kt = 0; kt < KT; ++kt) {
    int ktq = kt * 4 + quad;
    bf16x8 af[4];
#pragma unroll
    for (int rt = 0; rt < 4; ++rt) af[rt] = gnn_afrag(As, rt, ktq, l16);
#pragma unroll
    for (int ct = 0; ct < CT; ++ct) {
      bf16x8 bf = gnn_bfrag(pk, wave * CT + ct, kt, KT, lane);
#pragma unroll
      for (int rt = 0; rt < 4; ++rt)
        acc[rt][ct] = __builtin_amdgcn_mfma_f32_16x16x32_bf16(af[rt], bf, acc[rt][ct], 0, 0, 0);
    }
  }

#pragma unroll
  for (int ct = 0; ct < CT; ++ct) {
    int col = (wave * CT + ct) * 16 + l16;
    float bv = bias[col];
#pragma unroll
    for (int rt = 0; rt < 4; ++rt) {
      long row = row0 + rt * 16 + quad * 4;
#pragma unroll
      for (int r = 0; r < 4; ++r) {
        float v = acc[rt][ct][r] + bv;
        if (ACT) v = fmaxf(v, 0.f);
        C[(row + r) * N + col] = gnn_f2bf(v);
      }
    }
  }
}

// ============================================================================
// MFMA GRU (standalone, round-8 proven): Y = GRUCell(m = T@Wc, h = X)
// ============================================================================
template<int RELU>
__global__ __launch_bounds__(256) void gnn_mgru(const u16* __restrict__ T, const u16* __restrict__ X,
                                                const u16* __restrict__ pkRZ,
                                                const u16* __restrict__ pkAI,
                                                const u16* __restrict__ pkAH,
                                                const float* __restrict__ bi, const float* __restrict__ bh,
                                                u16* __restrict__ Y) {
  __shared__ u16 Ts[64 * 128];
  __shared__ u16 Xs[64 * 128];
  const int tid = threadIdx.x;
  const int lane = tid & 63, wave = tid >> 6;
  const int quad = lane >> 4, l16 = lane & 15;
  const long row0 = (long)blockIdx.x * 64;
  gnn_stage_bf<128>(T, row0, Ts, tid);
  gnn_stage_bf<128>(X, row0, Xs, tid);
  __syncthreads();

  f32x4 zero4 = {0.f, 0.f, 0.f, 0.f};
  f32x4 ai[4][2], ah[4][2], rr[4][2];
#pragma unroll
  for (int rt = 0; rt < 4; ++rt)
#pragma unroll
    for (int c = 0; c < 2; ++c) { ai[rt][c] = zero4; ah[rt][c] = zero4; rr[rt][c] = zero4; }

#pragma unroll
  for (int kt = 0; kt < 4; ++kt) {
    int ktq = kt * 4 + quad;
    bf16x8 tf[4], xf[4];
#pragma unroll
    for (int rt = 0; rt < 4; ++rt) { tf[rt] = gnn_afrag(Ts, rt, ktq, l16); xf[rt] = gnn_afrag(Xs, rt, ktq, l16); }
#pragma unroll
    for (int c = 0; c < 2; ++c) {
      int ct = wave * 2 + c;
      bf16x8 bAI = gnn_bfrag(pkAI, ct, kt, 4, lane);
      bf16x8 bAH = gnn_bfrag(pkAH, ct, kt, 4, lane);
      bf16x8 bRT = gnn_bfrag(pkRZ, ct, kt,     8, lane);
      bf16x8 bRX = gnn_bfrag(pkRZ, ct, kt + 4, 8, lane);
#pragma unroll
      for (int rt = 0; rt < 4; ++rt) {
        ai[rt][c] = __builtin_amdgcn_mfma_f32_16x16x32_bf16(tf[rt], bAI, ai[rt][c], 0, 0, 0);
        ah[rt][c] = __builtin_amdgcn_mfma_f32_16x16x32_bf16(xf[rt], bAH, ah[rt][c], 0, 0, 0);
        rr[rt][c] = __builtin_amdgcn_mfma_f32_16x16x32_bf16(tf[rt], bRT, rr[rt][c], 0, 0, 0);
        rr[rt][c] = __builtin_amdgcn_mfma_f32_16x16x32_bf16(xf[rt], bRX, rr[rt][c], 0, 0, 0);
      }
    }
  }

  float brz[2], bzz[2], bin_[2], bhn[2];
#pragma unroll
  for (int c = 0; c < 2; ++c) {
    int col = (wave * 2 + c) * 16 + l16;
    brz[c]  = bi[col] + bh[col];
    bzz[c]  = bi[128 + col] + bh[128 + col];
    bin_[c] = bi[256 + col];
    bhn[c]  = bh[256 + col];
  }

  // n = tanh(ai + bi_n + r*(ah + bh_n))   (n overwrites ai)
#pragma unroll
  for (int rt = 0; rt < 4; ++rt)
#pragma unroll
    for (int c = 0; c < 2; ++c)
#pragma unroll
      for (int r = 0; r < 4; ++r) {
        float rv = gnn_sig(rr[rt][c][r] + brz[c]);
        ai[rt][c][r] = gnn_tanh(ai[rt][c][r] + bin_[c] + rv * (ah[rt][c][r] + bhn[c]));
      }

  // z gate
  f32x4 zz[4][2];
#pragma unroll
  for (int rt = 0; rt < 4; ++rt)
#pragma unroll
    for (int c = 0; c < 2; ++c) zz[rt][c] = zero4;
#pragma unroll
  for (int kt = 0; kt < 4; ++kt) {
    int ktq = kt * 4 + quad;
    bf16x8 tf[4], xf[4];
#pragma unroll
    for (int rt = 0; rt < 4; ++rt) { tf[rt] = gnn_afrag(Ts, rt, ktq, l16); xf[rt] = gnn_afrag(Xs, rt, ktq, l16); }
#pragma unroll
    for (int c = 0; c < 2; ++c) {
      int ct = wave * 2 + c;
      bf16x8 bZT = gnn_bfrag(pkRZ, 8 + ct, kt,     8, lane);
      bf16x8 bZX = gnn_bfrag(pkRZ, 8 + ct, kt + 4, 8, lane);
#pragma unroll
      for (int rt = 0; rt < 4; ++rt) {
        zz[rt][c] = __builtin_amdgcn_mfma_f32_16x16x32_bf16(tf[rt], bZT, zz[rt][c], 0, 0, 0);
        zz[rt][c] = __builtin_amdgcn_mfma_f32_16x16x32_bf16(xf[rt], bZX, zz[rt][c], 0, 0, 0);
      }
    }
  }

  // combine + store (h from Xs LDS)
#pragma unroll
  for (int rt = 0; rt < 4; ++rt)
#pragma unroll
    for (int c = 0; c < 2; ++c) {
      int col = (wave * 2 + c) * 16 + l16;
      int rowl = rt * 16 + quad * 4;
#pragma unroll
      for (int r = 0; r < 4; ++r) {
        float z = gnn_sig(zz[rt][c][r] + bzz[c]);
        float h = gnn_lds_get(Xs, rowl + r, col);
        float v = (1.f - z) * ai[rt][c][r] + z * h;
        if (RELU) v = fmaxf(v, 0.f);
        Y[(row0 + rowl + r) * H + col] = gnn_f2bf(v);
      }
    }
}

// ============================================================================
// FUSED g1+g2: C = (relu(A@pk1+b1))@pk2 + b2  (both K=128, N=128)
// ============================================================================
__global__ __launch_bounds__(256) void gnn_g1g2(const u16* __restrict__ A,
                                                const u16* __restrict__ pk1, const float* __restrict__ b1,
                                                const u16* __restrict__ pk2, const float* __restrict__ b2,
                                                u16* __restrict__ C) {
  __shared__ u16 As[64 * 128];
  __shared__ u16 Ys[64 * 128];
  const int tid = threadIdx.x;
  const int lane = tid & 63, wave = tid >> 6;
  const int quad = lane >> 4, l16 = lane & 15;
  const long row0 = (long)blockIdx.x * 64;
  gnn_stage_bf<128>(A, row0, As, tid);
  __syncthreads();

  f32x4 zero4 = {0.f, 0.f, 0.f, 0.f};
  f32x4 acc[4][2];
#pragma unroll
  for (int rt = 0; rt < 4; ++rt)
#pragma unroll
    for (int ct = 0; ct < 2; ++ct) acc[rt][ct] = zero4;
#pragma unroll
  for (int kt = 0; kt < 4; ++kt) {
    int ktq = kt * 4 + quad;
    bf16x8 af[4];
#pragma unroll
    for (int rt = 0; rt < 4; ++rt) af[rt] = gnn_afrag(As, rt, ktq, l16);
#pragma unroll
    for (int ct = 0; ct < 2; ++ct) {
      bf16x8 bf = gnn_bfrag(pk1, wave * 2 + ct, kt, 4, lane);
#pragma unroll
      for (int rt = 0; rt < 4; ++rt)
        acc[rt][ct] = __builtin_amdgcn_mfma_f32_16x16x32_bf16(af[rt], bf, acc[rt][ct], 0, 0, 0);
    }
  }
#pragma unroll
  for (int ct = 0; ct < 2; ++ct) {
    int col = (wave * 2 + ct) * 16 + l16;
    float bv = b1[col];
#pragma unroll
    for (int rt = 0; rt < 4; ++rt) {
      int rowl = rt * 16 + quad * 4;
#pragma unroll
      for (int r = 0; r < 4; ++r)
        gnn_lds_put(Ys, rowl + r, col, fmaxf(acc[rt][ct][r] + bv, 0.f));
    }
  }
  __syncthreads();

  f32x4 acc2[4][2];
#pragma unroll
  for (int rt = 0; rt < 4; ++rt)
#pragma unroll
    for (int ct = 0; ct < 2; ++ct) acc2[rt][ct] = zero4;
#pragma unroll
  for (int kt = 0; kt < 4; ++kt) {
    int ktq = kt * 4 + quad;
    bf16x8 af[4];
#pragma unroll
    for (int rt = 0; rt < 4; ++rt) af[rt] = gnn_afrag(Ys, rt, ktq, l16);
#pragma unroll
    for (int ct = 0; ct < 2; ++ct) {
      bf16x8 bf = gnn_bfrag(pk2, wave * 2 + ct, kt, 4, lane);
#pragma unroll
      for (int rt = 0; rt < 4; ++rt)
        acc2[rt][ct] = __builtin_amdgcn_mfma_f32_16x16x32_bf16(af[rt], bf, acc2[rt][ct], 0, 0, 0);
    }
  }
#pragma unroll
  for (int ct = 0; ct < 2; ++ct) {
    int col = (wave * 2 + ct) * 16 + l16;
    float bv = b2[col];
#pragma unroll
    for (int rt = 0; rt < 4; ++rt) {
      long row = row0 + rt * 16 + quad * 4;
#pragma unroll
      for (int r = 0; r < 4; ++r)
        C[(row + r) * H + col] = gnn_f2bf(acc2[rt][ct][r] + bv);
    }
  }
}

// ============================================================================
// FUSED l1+l2: u2 = relu( relu(A@pk1 + gb[graph])@pk2 + b2 )
// ============================================================================
__global__ __launch_bounds__(256) void gnn_l1l2(const u16* __restrict__ A,
                                                const u16* __restrict__ pk1, const float* __restrict__ gb,
                                                const u16* __restrict__ pk2, const float* __restrict__ b2,
                                                u16* __restrict__ C) {
  __shared__ u16 As[64 * 128];   // 16KB
  __shared__ u16 Us[64 * 256];   // 32KB
  const int tid = threadIdx.x;
  const int lane = tid & 63, wave = tid >> 6;
  const int quad = lane >> 4, l16 = lane & 15;
  const long row0 = (long)blockIdx.x * 64;
  gnn_stage_bf<128>(A, row0, As, tid);
  __syncthreads();

  f32x4 zero4 = {0.f, 0.f, 0.f, 0.f};
  {
    f32x4 acc[4][4];
#pragma unroll
    for (int rt = 0; rt < 4; ++rt)
#pragma unroll
      for (int ct = 0; ct < 4; ++ct) acc[rt][ct] = zero4;
#pragma unroll
    for (int kt = 0; kt < 4; ++kt) {
      int ktq = kt * 4 + quad;
      bf16x8 af[4];
#pragma unroll
      for (int rt = 0; rt < 4; ++rt) af[rt] = gnn_afrag(As, rt, ktq, l16);
#pragma unroll
      for (int ct = 0; ct < 4; ++ct) {
        bf16x8 bf = gnn_bfrag(pk1, wave * 4 + ct, kt, 4, lane);
#pragma unroll
        for (int rt = 0; rt < 4; ++rt)
          acc[rt][ct] = __builtin_amdgcn_mfma_f32_16x16x32_bf16(af[rt], bf, acc[rt][ct], 0, 0, 0);
      }
    }
    const float* bp = gb + (row0 >> 12) * 256;
#pragma unroll
    for (int ct = 0; ct < 4; ++ct) {
      int col = (wave * 4 + ct) * 16 + l16;
      float bv = bp[col];
#pragma unroll
      for (int rt = 0; rt < 4; ++rt) {
        int rowl = rt * 16 + quad * 4;
#pragma unroll
        for (int r = 0; r < 4; ++r)
          gnn_lds_put(Us, rowl + r, col, fmaxf(acc[rt][ct][r] + bv, 0.f));
      }
    }
  }
  __syncthreads();

  f32x4 acc2[4][2];
#pragma unroll
  for (int rt = 0; rt < 4; ++rt)
#pragma unroll
    for (int ct = 0; ct < 2; ++ct) acc2[rt][ct] = zero4;
#pragma unroll
  for (int kt = 0; kt < 8; ++kt) {
    int ktq = kt * 4 + quad;
    bf16x8 af[4];
#pragma unroll
    for (int rt = 0; rt < 4; ++rt) af[rt] = gnn_afrag(Us, rt, ktq, l16);
#pragma unroll
    for (int ct = 0; ct < 2; ++ct) {
      bf16x8 bf = gnn_bfrag(pk2, wave * 2 + ct, kt, 8, lane);
#pragma unroll
      for (int rt = 0; rt < 4; ++rt)
        acc2[rt][ct] = __builtin_amdgcn_mfma_f32_16x16x32_bf16(af[rt], bf, acc2[rt][ct], 0, 0, 0);
    }
  }
#pragma unroll
  for (int ct = 0; ct < 2; ++ct) {
    int col = (wave * 2 + ct) * 16 + l16;
    float bv = b2[col];
#pragma unroll
    for (int rt = 0; rt < 4; ++rt) {
      long row = row0 + rt * 16 + quad * 4;
#pragma unroll
      for (int r = 0; r < 4; ++r)
        C[(row + r) * H + col] = gnn_f2bf(fmaxf(acc2[rt][ct][r] + bv, 0.f));
    }
  }
}

// ============================================================================
// fp32-input GEMM (emb1, K=16), bf16 output
// ============================================================================
#define GFMA(i, av) \
  acc[(i)*4+0] = fmaf((av), wv.x, acc[(i)*4+0]); \
  acc[(i)*4+1] = fmaf((av), wv.y, acc[(i)*4+1]); \
  acc[(i)*4+2] = fmaf((av), wv.z, acc[(i)*4+2]); \
  acc[(i)*4+3] = fmaf((av), wv.w, acc[(i)*4+3]);

__global__ __launch_bounds__(256) void gnn_gemm16(const float* __restrict__ A, const float* __restrict__ W,
                                                  const float* __restrict__ bias, u16* __restrict__ C,
                                                  int OUT) {
  const int K = 16;
  __shared__ float AsT[16][68];
  __shared__ float Ws[16][68];
  const int tid = threadIdx.x;
  const int tx = tid & 15, ty = tid >> 4;
  const long row0 = (long)blockIdx.y * 64;
  const int col0 = blockIdx.x * 64;
  const int lr  = tid >> 2;
  const int lk4 = (tid & 3) * 4;
  const int wk  = tid >> 4;
  const int wj4 = (tid & 15) * 4;
  float acc[16];
#pragma unroll
  for (int i = 0; i < 16; ++i) acc[i] = 0.f;

  {
    float4 a = *(const float4*)(A + (row0 + lr) * K + lk4);
    float4 w = *(const float4*)(W + (long)wk * OUT + col0 + wj4);
    AsT[lk4 + 0][lr] = a.x; AsT[lk4 + 1][lr] = a.y; AsT[lk4 + 2][lr] = a.z; AsT[lk4 + 3][lr] = a.w;
    *(float4*)(&Ws[wk][wj4]) = w;
    __syncthreads();
#pragma unroll
    for (int k = 0; k < 16; ++k) {
      float4 av = *(const float4*)(&AsT[k][ty * 4]);
      float4 wv = *(const float4*)(&Ws[k][tx * 4]);
      GFMA(0, av.x) GFMA(1, av.y) GFMA(2, av.z) GFMA(3, av.w)
    }
  }
#pragma unroll
  for (int i = 0; i < 4; ++i) {
    long row = row0 + ty * 4 + i;
    int j = col0 + tx * 4;
    float4 o;
    o.x = fmaxf(acc[i * 4 + 0] + bias[j + 0], 0.f);
    o.y = fmaxf(acc[i * 4 + 1] + bias[j + 1], 0.f);
    o.z = fmaxf(acc[i * 4 + 2] + bias[j + 2], 0.f);
    o.w = fmaxf(acc[i * 4 + 3] + bias[j + 3], 0.f);
    uint2 st;
    st.x = gnn_pack2bf(o.x, o.y);
    st.y = gnn_pack2bf(o.z, o.w);
    *(uint2*)(C + row * OUT + j) = st;
  }
}
#undef GFMA

// ============================================================================
// head: pool, per-graph bias, item-value init, final bound reduction
// ============================================================================
__global__ __launch_bounds__(128) void gnn_pool(const u16* __restrict__ X3, float* __restrict__ ge) {
  int b = blockIdx.x >> 3, chunk = blockIdx.x & 7, t = threadIdx.x;
  long base = ((long)b * PP + chunk * 512) * H;
  float acc = 0.f;
  for (int p = 0; p < 512; ++p) acc += gnn_bf2f(X3[base + (long)p * H + t]);
  atomicAdd(&ge[b * H + t], acc);
}

__global__ __launch_bounds__(256) void gnn_gbias(const float* __restrict__ ge, const float* __restrict__ Wl1b,
                                                 const float* __restrict__ bl1, float* __restrict__ gb) {
  __shared__ float g[128];
  int b = blockIdx.x, t = threadIdx.x;
  if (t < 128) g[t] = ge[b * H + t] * (1.f / 4096.f);
  __syncthreads();
  float acc = bl1[t];
  for (int k = 0; k < 128; ++k) acc = fmaf(g[k], Wl1b[k * 256 + t], acc);
  gb[b * 256 + t] = acc;
}

__global__ __launch_bounds__(256) void gnn_item(const float* __restrict__ iv, const int* __restrict__ vvs,
                                                float* __restrict__ out) {
  __shared__ float s[256];
  int b = blockIdx.x, t = threadIdx.x;
  float v = iv[b * 256 + t] * (float)vvs[(long)b * PP + t];
  s[t] = v; __syncthreads();
  for (int off = 128; off > 0; off >>= 1) {
    if (t < off) s[t] += s[t + off];
    __syncthreads();
  }
  if (t == 0) out[b] = s[0];
}

__global__ __launch_bounds__(256) void gnn_bound(const u16* __restrict__ U2, const float* __restrict__ wl3,
                                                 const float* __restrict__ bl3, const int* __restrict__ vvs,
                                                 float* __restrict__ out) {
  int tid = threadIdx.x;
  int wave = tid >> 6, lane = tid & 63;
  int b = blockIdx.x >> 6;
  long node0 = (long)blockIdx.x * 64 + wave * 16;
  float w0 = wl3[lane * 2], w1 = wl3[lane * 2 + 1];
  float bl = bl3[0];
  float acc = 0.f;
  for (int i = 0; i < 16; ++i) {
    long node = node0 + i;
    unsigned pv = *(const unsigned*)(U2 + node * H + lane * 2);
    union { unsigned u; float f; } lo, hi;
    lo.u = pv << 16; hi.u = pv & 0xFFFF0000u;
    float p = lo.f * w0 + hi.f * w1;
#pragma unroll
    for (int off = 32; off > 0; off >>= 1) p += __shfl_down(p, off);
    if (lane == 0) {
      int pp = (int)(node & (PP - 1));
      int m = pp >> 8, n = pp & 255;
      if (m != 0) {
        float dx = (float)(vvs[((long)b << 12) + n] - vvs[((long)b << 12) + pp]);
        acc += (p + bl) * dx;
      }
    }
  }
  __shared__ float s[4];
  if (lane == 0) s[wave] = acc;
  __syncthreads();
  if (tid == 0) atomicAdd(&out[b], s[0] + s[1] + s[2] + s[3]);
}

// ============================================================================
extern "C" void kernel_launch(void* const* d_in, const int* in_sizes, int n_in,
                              void* d_out, int out_size, void* d_ws, size_t ws_size,
                              hipStream_t stream) {
  const float* G      = (const float*)d_in[0];
  const int*   ei     = (const int*)d_in[1];
  const int*   esrc   = ei;
  const int*   edst   = ei + EDGES;
  const float* ew     = (const float*)d_in[2];
  const int*   vvs    = (const int*)d_in[4];
  const float* iv     = (const float*)d_in[5];
  const float* W_emb1 = (const float*)d_in[6];
  const float* b_emb1 = (const float*)d_in[7];
  const float* W_emb2 = (const float*)d_in[8];
  const float* b_emb2 = (const float*)d_in[9];
  const float* c1_W   = (const float*)d_in[10];
  const float* c1_wi  = (const float*)d_in[11];
  const float* c1_wh  = (const float*)d_in[12];
  const float* c1_bi  = (const float*)d_in[13];
  const float* c1_bh  = (const float*)d_in[14];
  const float* c2_W   = (const float*)d_in[15];
  const float* c2_wi  = (const float*)d_in[16];
  const float* c2_wh  = (const float*)d_in[17];
  const float* c2_bi  = (const float*)d_in[18];
  const float* c2_bh  = (const float*)d_in[19];
  const float* W_g1   = (const float*)d_in[20];
  const float* b_g1   = (const float*)d_in[21];
  const float* W_g2   = (const float*)d_in[22];
  const float* b_g2   = (const float*)d_in[23];
  const float* W_l1   = (const float*)d_in[24];
  const float* b_l1   = (const float*)d_in[25];
  const float* W_l2   = (const float*)d_in[26];
  const float* b_l2   = (const float*)d_in[27];
  const float* W_l3   = (const float*)d_in[28];
  const float* b_l3   = (const float*)d_in[29];
  float* out = (float*)d_out;
  (void)in_sizes; (void)n_in; (void)out_size; (void)ws_size;

  // ---- workspace carve (~135 MiB) ----
  char* wsb = (char*)d_ws;
  size_t off = 0;
  auto carve = [&](size_t bytes) -> char* {
    char* p = wsb + off;
    off += (bytes + 255) & ~(size_t)255;
    return p;
  };
  u16*   xa     = (u16*)carve(sizeof(u16) * (size_t)NODES * H);
  u16*   xc     = (u16*)carve(sizeof(u16) * (size_t)NODES * H);
  u16*   tb     = (u16*)carve(sizeof(u16) * (size_t)NODES * H);
  float* Wc     = (float*)carve(sizeof(float) * 4 * H * 384);
  float* whT    = (float*)carve(sizeof(float) * 2 * H * 384);
  u16*   pk     = (u16*)carve(sizeof(u16) * 507904);
  int*   rowptr = (int*)carve(sizeof(int) * (NODES + 1));
  int*   pcur   = (int*)carve(sizeof(int) * 128);
  int*   pbase  = (int*)carve(sizeof(int) * 128);
  uint2* stage  = (uint2*)carve(sizeof(uint2) * (size_t)128 * CAPP);
  unsigned* epack = (unsigned*)carve(sizeof(unsigned) * EDGES);
  float* ge     = (float*)carve(sizeof(float) * NB * H);
  float* gb     = (float*)carve(sizeof(float) * NB * 256);

  u16* pkRZ[4]; u16* pkAI[4]; u16* pkAH[4];
  for (int l = 0; l < 4; ++l) {
    pkRZ[l] = pk + (long)l * LYRE;
    pkAI[l] = pk + (long)l * LYRE + RZE;
    pkAH[l] = pk + (long)l * LYRE + RZE + AIE;
  }
  u16* pe2 = pk + 4 * LYRE;
  u16* pg1 = pe2 + 16384;
  u16* pg2 = pe2 + 32768;
  u16* pl1 = pe2 + 49152;
  u16* pl2 = pe2 + 81920;

  // ---- CSR build ----
  hipMemsetAsync(ge, 0, sizeof(float) * NB * H, stream);
  gnn_pinit<<<1, 128, 0, stream>>>(pcur);
  gnn_bin1<<<B1_BLOCKS, 256, 0, stream>>>(esrc, edst, ew, pcur, stage);
  gnn_pscan<<<1, 128, 0, stream>>>(pcur, pbase);
  gnn_bin2<<<128, 256, 0, stream>>>(stage, pcur, pbase, rowptr, epack);

  // ---- weight prep + pack (consolidated) ----
  gnn_prep_wc_all<<<512, 384, 0, stream>>>(c1_W, c1_wi, c2_W, c2_wi, Wc);
  gnn_prep_whT<<<256, 384, 0, stream>>>(c1_wh, c2_wh, whT);
  gnn_pack_layers<<<768, 64, 0, stream>>>(Wc, whT, pk);
  gnn_pack_misc<<<224, 64, 0, stream>>>(W_emb2, W_g1, W_g2, W_l1, W_l2, pk);

  // ---- embeddings: G -> xa -> xc ----
  gnn_gemm16<<<dim3(2, NODES / 64), 256, 0, stream>>>(G, W_emb1, b_emb1, xa, 128);
  gnn_mgemm<128, 128, 1><<<NODES / 64, 256, 0, stream>>>(xa, pe2, b_emb2, xc);

  // ---- conv1 (x in xc): separate agg (occupancy) + mgru (MFMA) ----
  gnn_agg<<<NODES / 4, 256, 0, stream>>>(xc, rowptr, epack, tb);
  gnn_mgru<0><<<NODES / 64, 256, 0, stream>>>(tb, xc, pkRZ[0], pkAI[0], pkAH[0], c1_bi, c1_bh, xa);
  gnn_agg<<<NODES / 4, 256, 0, stream>>>(xa, rowptr, epack, tb);
  gnn_mgru<1><<<NODES / 64, 256, 0, stream>>>(tb, xa, pkRZ[1], pkAI[1], pkAH[1], c1_bi, c1_bh, xc);

  // ---- conv2 ----
  gnn_agg<<<NODES / 4, 256, 0, stream>>>(xc, rowptr, epack, tb);
  gnn_mgru<0><<<NODES / 64, 256, 0, stream>>>(tb, xc, pkRZ[2], pkAI[2], pkAH[2], c2_bi, c2_bh, xa);
  gnn_agg<<<NODES / 4, 256, 0, stream>>>(xa, rowptr, epack, tb);
  gnn_mgru<1><<<NODES / 64, 256, 0, stream>>>(tb, xa, pkRZ[3], pkAI[3], pkAH[3], c2_bi, c2_bh, xc);

  // ---- head GEMMs fused: xc -> tb (x3) ----
  gnn_g1g2<<<NODES / 64, 256, 0, stream>>>(xc, pg1, b_g1, pg2, b_g2, tb);

  // ---- pool + per-graph bias (folds ge @ W_l1[128:] + b_l1) ----
  gnn_pool<<<NB * 8, 128, 0, stream>>>(tb, ge);
  gnn_gbias<<<NB, 256, 0, stream>>>(ge, W_l1 + 128 * 256, b_l1, gb);

  // ---- MLP fused l1+l2: tb -> xa (u2) ----
  gnn_l1l2<<<NODES / 64, 256, 0, stream>>>(tb, pl1, gb, pl2, b_l2, xa);

  // ---- bound ----
  gnn_item<<<NB, 256, 0, stream>>>(iv, vvs, out);
  gnn_bound<<<NODES / 64, 256, 0, stream>>>(xa, W_l3, b_l3, vvs, out);
}